// Round 12
// baseline (741.122 us; speedup 1.0000x reference)
//
#include <hip/hip_runtime.h>
#include <math.h>

#define DIM 1024
#define SEQ 1024
#define BATCH 4
#define NHEADS 16
#define HEADD 64
#define MLP_DIM 4096

typedef short short8 __attribute__((ext_vector_type(8)));
typedef float f32x4 __attribute__((ext_vector_type(4)));
#define MFMA(a, b, c) __builtin_amdgcn_mfma_f32_16x16x32_bf16(a, b, c, 0, 0, 0)

__device__ __forceinline__ ushort f2b(float x) {
  unsigned u = __float_as_uint(x);
  unsigned r = (u + 0x7FFFu + ((u >> 16) & 1u)) >> 16;
  return (ushort)r;
}
__device__ __forceinline__ float b2f(ushort h) {
  return __uint_as_float(((unsigned)h) << 16);
}

__device__ __forceinline__ void g2l16(const void* g, void* l) {
  __builtin_amdgcn_global_load_lds((const __attribute__((address_space(1))) void*)g,
                                   (__attribute__((address_space(3))) void*)l, 16, 0, 0);
}

// bijective XCD-aware block swizzle over (x,y); z untouched (split-K planes
// share the same tile->XCD banding). Requires gx*gy % 8 == 0.
__device__ __forceinline__ void xcd_swz(int& bx, int& by) {
  int gx = gridDim.x;
  int id = blockIdx.x + gx * blockIdx.y;
  int cpx = (gx * gridDim.y) >> 3;
  int sid = (id & 7) * cpx + (id >> 3);
  bx = sid % gx;
  by = sid / gx;
}

// convert 8 floats (scaled) to bf16 hi + residual lo short8
__device__ __forceinline__ void cvt8(const float* f, float scale, short8& hi, short8& lo) {
#pragma unroll
  for (int i = 0; i < 8; i++) {
    float v = f[i] * scale;
    ushort hv = f2b(v);
    hi[i] = (short)hv;
    lo[i] = (short)f2b(v - b2f(hv));
  }
}

// ---------------- LayerNorm -> bf16 hi/lo ----------------
__global__ __launch_bounds__(256) void ln_kernel(const float* __restrict__ x,
                                                 const float* __restrict__ g,
                                                 const float* __restrict__ b,
                                                 ushort* __restrict__ ohi,
                                                 ushort* __restrict__ olo) {
  int row = blockIdx.x;
  int t = threadIdx.x;
  const float* xr = x + (size_t)row * DIM;
  float4 v = *(const float4*)(xr + t * 4);
  float s  = v.x + v.y + v.z + v.w;
  float sq = v.x * v.x + v.y * v.y + v.z * v.z + v.w * v.w;
#pragma unroll
  for (int off = 32; off > 0; off >>= 1) {
    s  += __shfl_down(s, off);
    sq += __shfl_down(sq, off);
  }
  __shared__ float red_s[4], red_q[4];
  __shared__ float mu_s, inv_s;
  int wid = t >> 6;
  if ((t & 63) == 0) { red_s[wid] = s; red_q[wid] = sq; }
  __syncthreads();
  if (t == 0) {
    float S  = red_s[0] + red_s[1] + red_s[2] + red_s[3];
    float Sq = red_q[0] + red_q[1] + red_q[2] + red_q[3];
    float mu  = S * (1.0f / DIM);
    float var = Sq * (1.0f / DIM) - mu * mu;
    mu_s  = mu;
    inv_s = 1.0f / sqrtf(var + 1e-5f);
  }
  __syncthreads();
  float mu = mu_s, inv = inv_s;
  float4 gv = *(const float4*)(g + t * 4);
  float4 bv = *(const float4*)(b + t * 4);
  float o0 = (v.x - mu) * inv * gv.x + bv.x;
  float o1 = (v.y - mu) * inv * gv.y + bv.y;
  float o2 = (v.z - mu) * inv * gv.z + bv.z;
  float o3 = (v.w - mu) * inv * gv.w + bv.w;
  ushort4 hv, lv;
  hv.x = f2b(o0); lv.x = f2b(o0 - b2f(hv.x));
  hv.y = f2b(o1); lv.y = f2b(o1 - b2f(hv.y));
  hv.z = f2b(o2); lv.z = f2b(o2 - b2f(hv.z));
  hv.w = f2b(o3); lv.w = f2b(o3 - b2f(hv.w));
  *(ushort4*)(ohi + (size_t)row * DIM + t * 4) = hv;
  *(ushort4*)(olo + (size_t)row * DIM + t * 4) = lv;
}

// ---------------- weight prep: transpose KxN fp32 -> NxK bf16 hi/lo --------
__global__ __launch_bounds__(256) void wprep_kernel(const float* __restrict__ W,
                                                    ushort* __restrict__ Whi,
                                                    ushort* __restrict__ Wlo,
                                                    int Kd, int Nd) {
  __shared__ float tile[64][65];
  const int t = threadIdx.x;
  const int n0 = blockIdx.x * 64, k0 = blockIdx.y * 64;
  const int r = t >> 4, c4 = (t & 15) * 4;
#pragma unroll
  for (int i = 0; i < 4; i++) {
    float4 v = *(const float4*)&W[(size_t)(k0 + r + i * 16) * Nd + n0 + c4];
    tile[r + i * 16][c4 + 0] = v.x;
    tile[r + i * 16][c4 + 1] = v.y;
    tile[r + i * 16][c4 + 2] = v.z;
    tile[r + i * 16][c4 + 3] = v.w;
  }
  __syncthreads();
#pragma unroll
  for (int i = 0; i < 4; i++) {
    int nr = r + i * 16;
    float x0 = tile[c4 + 0][nr], x1 = tile[c4 + 1][nr];
    float x2 = tile[c4 + 2][nr], x3 = tile[c4 + 3][nr];
    ushort4 hv, lv;
    hv.x = f2b(x0); lv.x = f2b(x0 - b2f(hv.x));
    hv.y = f2b(x1); lv.y = f2b(x1 - b2f(hv.y));
    hv.z = f2b(x2); lv.z = f2b(x2 - b2f(hv.z));
    hv.w = f2b(x3); lv.w = f2b(x3 - b2f(hv.w));
    *(ushort4*)&Whi[(size_t)(n0 + nr) * Kd + k0 + c4] = hv;
    *(ushort4*)&Wlo[(size_t)(n0 + nr) * Kd + k0 + c4] = lv;
  }
}

// ---------------- split-bf16 MFMA GEMM (validated R4/R9/R11) ----------------
// Klen = K extent this block accumulates; Kstride = row stride; Koff = start.
template <int MS, int NS, int EPI>
__device__ __forceinline__ void mgemm_body(
    const ushort* __restrict__ Ahi, const ushort* __restrict__ Alo,
    const ushort* __restrict__ Bhi, const ushort* __restrict__ Blo,
    const float* __restrict__ bias, const float* __restrict__ res,
    float* __restrict__ Cf, ushort* __restrict__ Chi, ushort* __restrict__ Clo,
    int M, int N, int Klen, int Kstride, int Koff) {
  constexpr int ASUB = 2 * MS;
  constexpr int BSUB = 2 * NS;
  constexpr int TOT = 2 * (ASUB + BSUB);
  constexpr int PW = TOT / 4;
  __shared__ ushort lds[TOT * 512];

  int bx, by;
  xcd_swz(bx, by);
  const int t = threadIdx.x;
  const int l = t & 63;
  const int wid = t >> 6;
  const int wm = wid >> 1, wn = wid & 1;
  const int m0 = by * (ASUB * 16);
  const int n0 = bx * (BSUB * 16);
  const int lr = l & 15;
  const int lk = (l >> 4) * 8;

  const ushort* gsrc[PW];
  ushort* ldst[PW];
#pragma unroll
  for (int i = 0; i < PW; i++) {
    int j = wid * PW + i;
    const ushort* base;
    int rowbase, slot;
    if (j < 2 * ASUB) {
      int plane = j & 1, sub = j >> 1;
      base = plane ? Alo : Ahi;
      rowbase = m0 + sub * 16;
      slot = plane * ASUB + sub;
    } else {
      int jb = j - 2 * ASUB;
      int plane = jb & 1, sub = jb >> 1;
      base = plane ? Blo : Bhi;
      rowbase = n0 + sub * 16;
      slot = 2 * ASUB + plane * BSUB + sub;
    }
    gsrc[i] = base + (size_t)(rowbase + lr) * Kstride + Koff + lk;
    ldst[i] = &lds[slot * 512];
  }

  f32x4 acc[MS][NS] = {};

  for (int k0 = 0; k0 < Klen; k0 += 32) {
    __syncthreads();
#pragma unroll
    for (int i = 0; i < PW; i++) {
      g2l16(gsrc[i], ldst[i]);
      gsrc[i] += 32;
    }
    __syncthreads();

    short8 ah[MS], al[MS], bh[NS], bl[NS];
#pragma unroll
    for (int mi = 0; mi < MS; mi++) {
      ah[mi] = *(const short8*)&lds[(wm * MS + mi) * 512 + l * 8];
      al[mi] = *(const short8*)&lds[(ASUB + wm * MS + mi) * 512 + l * 8];
    }
#pragma unroll
    for (int ni = 0; ni < NS; ni++) {
      bh[ni] = *(const short8*)&lds[(2 * ASUB + wn * NS + ni) * 512 + l * 8];
      bl[ni] = *(const short8*)&lds[(2 * ASUB + BSUB + wn * NS + ni) * 512 + l * 8];
    }
#pragma unroll
    for (int mi = 0; mi < MS; mi++)
#pragma unroll
      for (int ni = 0; ni < NS; ni++) {
        acc[mi][ni] = MFMA(ah[mi], bh[ni], acc[mi][ni]);
        acc[mi][ni] = MFMA(ah[mi], bl[ni], acc[mi][ni]);
        acc[mi][ni] = MFMA(al[mi], bh[ni], acc[mi][ni]);
      }
  }

  const int orow0 = m0 + wm * (MS * 16);
  const int ocol0 = n0 + wn * (NS * 16);
#pragma unroll
  for (int mi = 0; mi < MS; mi++) {
#pragma unroll
    for (int r = 0; r < 4; r++) {
      int row = orow0 + mi * 16 + (l >> 4) * 4 + r;
#pragma unroll
      for (int ni = 0; ni < NS; ni++) {
        int col = ocol0 + ni * 16 + lr;
        size_t idx = (size_t)row * N + col;
        float v = acc[mi][ni][r];
        if (EPI == 0) {
          Cf[idx] = v;
        } else if (EPI == 1) {
          Cf[idx] = v + res[idx];
        } else if (EPI == 2) {
          v += bias[col];
          v = 0.5f * v * (1.0f + erff(v * 0.70710678118654752f));
          ushort h = f2b(v);
          Chi[idx] = h;
          Clo[idx] = f2b(v - b2f(h));
        } else {
          Cf[idx] = v + bias[col] + res[idx];
        }
      }
    }
  }
}

template <int MS, int NS, int EPI, int MINW>
__global__ __launch_bounds__(256, MINW) void mgemm_kernel(
    const ushort* __restrict__ Ahi, const ushort* __restrict__ Alo,
    const ushort* __restrict__ Bhi, const ushort* __restrict__ Blo,
    const float* __restrict__ bias, const float* __restrict__ res,
    float* __restrict__ Cf, ushort* __restrict__ Chi, ushort* __restrict__ Clo,
    int M, int N, int K) {
  mgemm_body<MS, NS, EPI>(Ahi, Alo, Bhi, Blo, bias, res, Cf, Chi, Clo,
                          M, N, K, K, 0);
}

// split-K=2: z selects K-half and partial buffer (fp32, EPI=0).
template <int MS, int NS, int MINW>
__global__ __launch_bounds__(256, MINW) void mgemm_sk(
    const ushort* __restrict__ Ahi, const ushort* __restrict__ Alo,
    const ushort* __restrict__ Bhi, const ushort* __restrict__ Blo,
    float* __restrict__ P0, float* __restrict__ P1,
    int M, int N, int K, int Khalf) {
  float* P = blockIdx.z ? P1 : P0;
  mgemm_body<MS, NS, 0>(Ahi, Alo, Bhi, Blo, nullptr, nullptr, P, nullptr,
                        nullptr, M, N, Khalf, K, blockIdx.z * Khalf);
}

// out = P0 + P1 [+ bias] + res   (memory-bound, float4, N must be pow2)
template <bool BIAS>
__global__ __launch_bounds__(256) void red2_kernel(const float* __restrict__ P0,
                                                   const float* __restrict__ P1,
                                                   const float* __restrict__ bias,
                                                   const float* __restrict__ res,
                                                   float* __restrict__ out) {
  size_t i = (size_t)blockIdx.x * 256 + threadIdx.x;   // float4 index
  size_t e = i * 4;
  float4 a = *(const float4*)(P0 + e);
  float4 b = *(const float4*)(P1 + e);
  float4 r = *(const float4*)(res + e);
  float4 o;
  o.x = a.x + b.x + r.x;
  o.y = a.y + b.y + r.y;
  o.z = a.z + b.z + r.z;
  o.w = a.w + b.w + r.w;
  if (BIAS) {
    float4 bb = *(const float4*)(bias + (e & (DIM - 1)));
    o.x += bb.x; o.y += bb.y; o.z += bb.z; o.w += bb.w;
  }
  *(float4*)(out + e) = o;
}

__global__ __launch_bounds__(256, 2) void qkv_mfma(
    const ushort* __restrict__ Ahi, const ushort* __restrict__ Alo,
    const ushort* __restrict__ Wqh, const ushort* __restrict__ Wql,
    const ushort* __restrict__ Wkh, const ushort* __restrict__ Wkl,
    const ushort* __restrict__ Wvh, const ushort* __restrict__ Wvl,
    float* __restrict__ Qo, float* __restrict__ Ko, float* __restrict__ Vo) {
  const ushort* bh = (blockIdx.z == 0) ? Wqh : (blockIdx.z == 1) ? Wkh : Wvh;
  const ushort* bl = (blockIdx.z == 0) ? Wql : (blockIdx.z == 1) ? Wkl : Wvl;
  float* C = (blockIdx.z == 0) ? Qo : (blockIdx.z == 1) ? Ko : Vo;
  mgemm_body<4, 4, 0>(Ahi, Alo, bh, bl, nullptr, nullptr, C, nullptr, nullptr,
                      4096, DIM, DIM, DIM, 0);
}

// ---------------- MFMA flash attention (validated R9) ----------------
#define KSLOT(s, ks, pl) (((s) * 2 + (ks)) * 1024 + (pl) * 512)
#define VSLOT(d, ks, pl) (8192 + ((d) * 2 + (ks)) * 1024 + (pl) * 512)
#define PSLOT(w, qf, ks, pl) (16384 + (w) * 4096 + (((qf) * 2 + (ks)) * 2 + (pl)) * 512)

__global__ __launch_bounds__(256, 2) void attn_mfma(const float* __restrict__ Q,
                                                    const float* __restrict__ K,
                                                    const float* __restrict__ V,
                                                    ushort* __restrict__ Ohi,
                                                    ushort* __restrict__ Olo) {
  __shared__ ushort lds[32768];   // 64 KB: K 16K + V^T 16K + P 4x8K
  const int qt = blockIdx.x;      // 0..7
  const int n  = blockIdx.y;      // 0..15
  const int bi = blockIdx.z;      // 0..3
  const size_t headoff = ((size_t)bi * SEQ + (size_t)n * HEADD) * DIM;
  const float* Qh = Q + headoff;
  const float* Kh = K + headoff;
  const float* Vh = V + headoff;
  const int t = threadIdx.x;
  const int l = t & 63;
  const int w = t >> 6;
  const int lq = l & 15;
  const int h = l >> 4;
  const int qrow = qt * 128 + w * 32;   // wave's first q row

  // Q fragments in registers: [qf][kstep] hi/lo
  short8 qfh[2][2], qfl[2][2];
#pragma unroll
  for (int qf = 0; qf < 2; qf++) {
    const float* qp = Qh + (size_t)(qrow + qf * 16 + lq) * 64 + h * 8;
#pragma unroll
    for (int ks = 0; ks < 2; ks++) {
      float f[8];
      float4 a = *(const float4*)(qp + ks * 32);
      float4 b = *(const float4*)(qp + ks * 32 + 4);
      f[0]=a.x; f[1]=a.y; f[2]=a.z; f[3]=a.w; f[4]=b.x; f[5]=b.y; f[6]=b.z; f[7]=b.w;
      cvt8(f, 1.0f, qfh[qf][ks], qfl[qf][ks]);
    }
  }

  f32x4 accO[4][2] = {};          // [df][qf], col=q lane-local
  float m_run[2] = {-1e30f, -1e30f};
  float l_run[2] = {0.0f, 0.0f};

  for (int tdx = 0; tdx < SEQ / 64; tdx++) {
    const int kvbase = tdx * 64;
    __syncthreads();
    // ---- stage K (wave w -> kv-subtile w), scale 1/8 folded (exact) ----
    {
      const float* kp = Kh + (size_t)(kvbase + 16 * w + lq) * 64 + h * 8;
#pragma unroll
      for (int ks = 0; ks < 2; ks++) {
        float f[8];
        float4 a = *(const float4*)(kp + ks * 32);
        float4 b = *(const float4*)(kp + ks * 32 + 4);
        f[0]=a.x; f[1]=a.y; f[2]=a.z; f[3]=a.w; f[4]=b.x; f[5]=b.y; f[6]=b.z; f[7]=b.w;
        short8 hi, lo;
        cvt8(f, 0.125f, hi, lo);
        *(short8*)&lds[KSLOT(w, ks, 0) + l * 8] = hi;
        *(short8*)&lds[KSLOT(w, ks, 1) + l * 8] = lo;
      }
    }
    // ---- stage V^T (wave w -> d-subtile w) ----
    {
#pragma unroll
      for (int ks = 0; ks < 2; ks++) {
        float f[8];
#pragma unroll
        for (int j = 0; j < 8; j++)
          f[j] = Vh[(size_t)(kvbase + ks * 32 + h * 8 + j) * 64 + 16 * w + lq];
        short8 hi, lo;
        cvt8(f, 1.0f, hi, lo);
        *(short8*)&lds[VSLOT(w, ks, 0) + l * 8] = hi;
        *(short8*)&lds[VSLOT(w, ks, 1) + l * 8] = lo;
      }
    }
    __syncthreads();

    // ---- S^T = K @ Q^T : acc row=kv, col=q (3-pass split) ----
    f32x4 accS[4][2] = {};
#pragma unroll
    for (int ks = 0; ks < 2; ks++) {
      short8 kh[4], kl[4];
#pragma unroll
      for (int s = 0; s < 4; s++) {
        kh[s] = *(const short8*)&lds[KSLOT(s, ks, 0) + l * 8];
        kl[s] = *(const short8*)&lds[KSLOT(s, ks, 1) + l * 8];
      }
#pragma unroll
      for (int s = 0; s < 4; s++)
#pragma unroll
        for (int qf = 0; qf < 2; qf++) {
          accS[s][qf] = MFMA(kh[s], qfh[qf][ks], accS[s][qf]);
          accS[s][qf] = MFMA(kh[s], qfl[qf][ks], accS[s][qf]);
          accS[s][qf] = MFMA(kl[s], qfh[qf][ks], accS[s][qf]);
        }
    }

    // ---- online softmax (per q = lane&15, per qf) ----
    float corr[2];
#pragma unroll
    for (int qf = 0; qf < 2; qf++) {
      float tmax = -1e30f;
#pragma unroll
      for (int s = 0; s < 4; s++)
#pragma unroll
        for (int r = 0; r < 4; r++) tmax = fmaxf(tmax, accS[s][qf][r]);
      tmax = fmaxf(tmax, __shfl_xor(tmax, 16));
      tmax = fmaxf(tmax, __shfl_xor(tmax, 32));
      float mnew = fmaxf(m_run[qf], tmax);
      float c = __expf(m_run[qf] - mnew);
      m_run[qf] = mnew;
      corr[qf] = c;
      float tsum = 0.0f;
#pragma unroll
      for (int s = 0; s < 4; s++)
#pragma unroll
        for (int r = 0; r < 4; r++) {
          float p = __expf(accS[s][qf][r] - mnew);
          accS[s][qf][r] = p;
          tsum += p;
        }
      tsum += __shfl_xor(tsum, 16);
      tsum += __shfl_xor(tsum, 32);
      l_run[qf] = l_run[qf] * c + tsum;
    }

    // ---- pack P -> wave-private LDS in B-fragment order ----
#pragma unroll
    for (int qf = 0; qf < 2; qf++)
#pragma unroll
      for (int s = 0; s < 4; s++) {
        f32x4 p = accS[s][qf];
        ushort4 hv, lv;
        hv.x = f2b(p[0]); lv.x = f2b(p[0] - b2f(hv.x));
        hv.y = f2b(p[1]); lv.y = f2b(p[1] - b2f(hv.y));
        hv.z = f2b(p[2]); lv.z = f2b(p[2] - b2f(hv.z));
        hv.w = f2b(p[3]); lv.w = f2b(p[3] - b2f(hv.w));
        int ib = (((s & 1) * 2) + (h >> 1)) * 128 + lq * 8 + (h & 1) * 4;
        *(ushort4*)&lds[PSLOT(w, qf, s >> 1, 0) + ib] = hv;
        *(ushort4*)&lds[PSLOT(w, qf, s >> 1, 1) + ib] = lv;
      }

    // ---- rescale O accumulator (corr lane-local: col=q) ----
#pragma unroll
    for (int df = 0; df < 4; df++)
#pragma unroll
      for (int qf = 0; qf < 2; qf++)
#pragma unroll
        for (int r = 0; r < 4; r++) accO[df][qf][r] *= corr[qf];

    // ---- O^T += V^T @ P^T (3-pass split) ----
#pragma unroll
    for (int ks = 0; ks < 2; ks++) {
      short8 vh[4], vl[4], ph[2], pl[2];
#pragma unroll
      for (int d = 0; d < 4; d++) {
        vh[d] = *(const short8*)&lds[VSLOT(d, ks, 0) + l * 8];
        vl[d] = *(const short8*)&lds[VSLOT(d, ks, 1) + l * 8];
      }
#pragma unroll
      for (int qf = 0; qf < 2; qf++) {
        ph[qf] = *(const short8*)&lds[PSLOT(w, qf, ks, 0) + l * 8];
        pl[qf] = *(const short8*)&lds[PSLOT(w, qf, ks, 1) + l * 8];
      }
#pragma unroll
      for (int d = 0; d < 4; d++)
#pragma unroll
        for (int qf = 0; qf < 2; qf++) {
          accO[d][qf] = MFMA(vh[d], ph[qf], accO[d][qf]);
          accO[d][qf] = MFMA(vl[d], ph[qf], accO[d][qf]);
          accO[d][qf] = MFMA(vh[d], pl[qf], accO[d][qf]);
        }
    }
  }

  // ---- epilogue: normalize + write bf16 hi/lo ----
#pragma unroll
  for (int qf = 0; qf < 2; qf++) {
    float inv = 1.0f / l_run[qf];
    int qg = qrow + qf * 16 + lq;
    size_t base = ((size_t)bi * SEQ + qg) * DIM + n * HEADD;
#pragma unroll
    for (int df = 0; df < 4; df++) {
      f32x4 o = accO[df][qf];
      float v0 = o[0] * inv, v1 = o[1] * inv, v2 = o[2] * inv, v3 = o[3] * inv;
      ushort4 hv, lv;
      hv.x = f2b(v0); lv.x = f2b(v0 - b2f(hv.x));
      hv.y = f2b(v1); lv.y = f2b(v1 - b2f(hv.y));
      hv.z = f2b(v2); lv.z = f2b(v2 - b2f(hv.z));
      hv.w = f2b(v3); lv.w = f2b(v3 - b2f(hv.w));
      size_t a = base + df * 16 + h * 4;
      *(ushort4*)(Ohi + a) = hv;
      *(ushort4*)(Olo + a) = lv;
    }
  }
}

// ---------------- launch ----------------
extern "C" void kernel_launch(void* const* d_in, const int* in_sizes, int n_in,
                              void* d_out, int out_size, void* d_ws, size_t ws_size,
                              hipStream_t stream) {
  const float* x    = (const float*)d_in[0];
  const float* Wq   = (const float*)d_in[1];
  const float* Wk   = (const float*)d_in[2];
  const float* Wv   = (const float*)d_in[3];
  const float* Wo   = (const float*)d_in[4];
  const float* W1   = (const float*)d_in[5];
  const float* b1   = (const float*)d_in[6];
  const float* W2   = (const float*)d_in[7];
  const float* b2   = (const float*)d_in[8];
  const float* gln1 = (const float*)d_in[9];
  const float* bln1 = (const float*)d_in[10];
  const float* gln2 = (const float*)d_in[11];
  const float* bln2 = (const float*)d_in[12];
  float* out = (float*)d_out;
  char* W = (char*)d_ws;

  const size_t MB = 1u << 20;
  ushort* Wqh = (ushort*)(W + 0 * MB);    // dead after qkv (step 2)
  ushort* Wql = (ushort*)(W + 2 * MB);
  ushort* Wkh = (ushort*)(W + 4 * MB);
  ushort* Wkl = (ushort*)(W + 6 * MB);
  ushort* Wvh = (ushort*)(W + 8 * MB);
  ushort* Wvl = (ushort*)(W + 10 * MB);
  ushort* Woh = (ushort*)(W + 12 * MB);   // dead after Wo main (step 4a)
  ushort* Wol = (ushort*)(W + 14 * MB);
  ushort* W1h = (ushort*)(W + 16 * MB);   // dead after W1 (step 6)
  ushort* W1l = (ushort*)(W + 24 * MB);
  ushort* W2h = (ushort*)(W + 32 * MB);   // live till step 7a
  ushort* W2l = (ushort*)(W + 40 * MB);
  float*  X2  = (float*) (W + 48 * MB);   // live steps 4b-7b
  ushort* Hhi = (ushort*)(W + 64 * MB);   // LN1 out (1-2); LN2 out (5-6)
  ushort* Hlo = (ushort*)(W + 72 * MB);
  float*  Qb  = (float*) (W + 80 * MB);   // QKV fp32, dead after attn (step 3)
  float*  Kb  = (float*) (W + 96 * MB);
  float*  Vb  = (float*) (W + 112 * MB);
  ushort* F1h = (ushort*)(W + 80 * MB);   // steps 6-7a
  ushort* F1l = (ushort*)(W + 112 * MB);
  ushort* Ohi = (ushort*)(W + 128 * MB);  // attn out, dead after step 4a
  ushort* Olo = (ushort*)(W + 136 * MB);
  // split-K partials (fp32, 16 MB each), placed in dead regions:
  float* P0wo = (float*)(W + 64 * MB);    // Hhi/Hlo dead between qkv and LN2
  float* P1wo = (float*)(W + 80 * MB);    // Qb dead after attn, before F1h
  float* P0w2 = (float*)(W + 0 * MB);     // QKV/Wo weights dead after step 4
  float* P1w2 = (float*)(W + 16 * MB);    // W1 weights dead after step 6

  // 0. weight prep
  wprep_kernel<<<dim3(16, 16), 256, 0, stream>>>(Wq, Wqh, Wql, DIM, DIM);
  wprep_kernel<<<dim3(16, 16), 256, 0, stream>>>(Wk, Wkh, Wkl, DIM, DIM);
  wprep_kernel<<<dim3(16, 16), 256, 0, stream>>>(Wv, Wvh, Wvl, DIM, DIM);
  wprep_kernel<<<dim3(16, 16), 256, 0, stream>>>(Wo, Woh, Wol, DIM, DIM);
  wprep_kernel<<<dim3(64, 16), 256, 0, stream>>>(W1, W1h, W1l, DIM, MLP_DIM);
  wprep_kernel<<<dim3(16, 64), 256, 0, stream>>>(W2, W2h, W2l, MLP_DIM, DIM);
  // 1. h = LN1(x)
  ln_kernel<<<4096, 256, 0, stream>>>(x, gln1, bln1, Hhi, Hlo);
  // 2. Q,K,V
  qkv_mfma<<<dim3(8, 32, 3), 256, 0, stream>>>(Hhi, Hlo, Wqh, Wql, Wkh, Wkl,
                                               Wvh, Wvl, Qb, Kb, Vb);
  // 3. attention
  attn_mfma<<<dim3(8, 16, 4), 256, 0, stream>>>(Qb, Kb, Vb, Ohi, Olo);
  // 4a. Wo split-K=2 partials; 4b. X2 = P0+P1+x
  mgemm_sk<2, 4, 4><<<dim3(8, 64, 2), 256, 0, stream>>>(
      Ohi, Olo, Woh, Wol, P0wo, P1wo, 4096, DIM, DIM, DIM / 2);
  red2_kernel<false><<<4096, 256, 0, stream>>>(P0wo, P1wo, nullptr, x, X2);
  // 5. h2 = LN2(X2)
  ln_kernel<<<4096, 256, 0, stream>>>(X2, gln2, bln2, Hhi, Hlo);
  // 6. f1 = gelu(h2 @ W1 + b1)
  mgemm_kernel<4, 4, 2, 2><<<dim3(32, 32), 256, 0, stream>>>(
      Hhi, Hlo, W1h, W1l, b1, nullptr, nullptr, F1h, F1l, 4096, MLP_DIM, DIM);
  // 7a. W2 split-K=2 partials; 7b. out = P0+P1+b2+X2
  mgemm_sk<2, 4, 4><<<dim3(8, 64, 2), 256, 0, stream>>>(
      F1h, F1l, W2h, W2l, P0w2, P1w2, 4096, DIM, MLP_DIM, MLP_DIM / 2);
  red2_kernel<true><<<4096, 256, 0, stream>>>(P0w2, P1w2, b2, X2, out);
}

// Round 15
// 676.127 us; speedup vs baseline: 1.0961x; 1.0961x over previous
//
#include <hip/hip_runtime.h>
#include <math.h>

#define DIM 1024
#define SEQ 1024
#define BATCH 4
#define NHEADS 16
#define HEADD 64
#define MLP_DIM 4096

typedef short short8 __attribute__((ext_vector_type(8)));
typedef float f32x4 __attribute__((ext_vector_type(4)));
#define MFMA(a, b, c) __builtin_amdgcn_mfma_f32_16x16x32_bf16(a, b, c, 0, 0, 0)

__device__ __forceinline__ ushort f2b(float x) {
  unsigned u = __float_as_uint(x);
  unsigned r = (u + 0x7FFFu + ((u >> 16) & 1u)) >> 16;
  return (ushort)r;
}
__device__ __forceinline__ float b2f(ushort h) {
  return __uint_as_float(((unsigned)h) << 16);
}

__device__ __forceinline__ void g2l16(const void* g, void* l) {
  __builtin_amdgcn_global_load_lds((const __attribute__((address_space(1))) void*)g,
                                   (__attribute__((address_space(3))) void*)l, 16, 0, 0);
}

// bijective XCD-aware block swizzle over (x,y); z untouched. gx*gy % 8 == 0.
__device__ __forceinline__ void xcd_swz(int& bx, int& by) {
  int gx = gridDim.x;
  int id = blockIdx.x + gx * blockIdx.y;
  int cpx = (gx * gridDim.y) >> 3;
  int sid = (id & 7) * cpx + (id >> 3);
  bx = sid % gx;
  by = sid / gx;
}

// convert 8 floats (scaled) to bf16 hi + residual lo short8
__device__ __forceinline__ void cvt8(const float* f, float scale, short8& hi, short8& lo) {
#pragma unroll
  for (int i = 0; i < 8; i++) {
    float v = f[i] * scale;
    ushort hv = f2b(v);
    hi[i] = (short)hv;
    lo[i] = (short)f2b(v - b2f(hv));
  }
}

// ---------------- LayerNorm -> bf16 hi/lo ----------------
__global__ __launch_bounds__(256) void ln_kernel(const float* __restrict__ x,
                                                 const float* __restrict__ g,
                                                 const float* __restrict__ b,
                                                 ushort* __restrict__ ohi,
                                                 ushort* __restrict__ olo) {
  int row = blockIdx.x;
  int t = threadIdx.x;
  const float* xr = x + (size_t)row * DIM;
  float4 v = *(const float4*)(xr + t * 4);
  float s  = v.x + v.y + v.z + v.w;
  float sq = v.x * v.x + v.y * v.y + v.z * v.z + v.w * v.w;
#pragma unroll
  for (int off = 32; off > 0; off >>= 1) {
    s  += __shfl_down(s, off);
    sq += __shfl_down(sq, off);
  }
  __shared__ float red_s[4], red_q[4];
  __shared__ float mu_s, inv_s;
  int wid = t >> 6;
  if ((t & 63) == 0) { red_s[wid] = s; red_q[wid] = sq; }
  __syncthreads();
  if (t == 0) {
    float S  = red_s[0] + red_s[1] + red_s[2] + red_s[3];
    float Sq = red_q[0] + red_q[1] + red_q[2] + red_q[3];
    float mu  = S * (1.0f / DIM);
    float var = Sq * (1.0f / DIM) - mu * mu;
    mu_s  = mu;
    inv_s = 1.0f / sqrtf(var + 1e-5f);
  }
  __syncthreads();
  float mu = mu_s, inv = inv_s;
  float4 gv = *(const float4*)(g + t * 4);
  float4 bv = *(const float4*)(b + t * 4);
  float o0 = (v.x - mu) * inv * gv.x + bv.x;
  float o1 = (v.y - mu) * inv * gv.y + bv.y;
  float o2 = (v.z - mu) * inv * gv.z + bv.z;
  float o3 = (v.w - mu) * inv * gv.w + bv.w;
  ushort4 hv, lv;
  hv.x = f2b(o0); lv.x = f2b(o0 - b2f(hv.x));
  hv.y = f2b(o1); lv.y = f2b(o1 - b2f(hv.y));
  hv.z = f2b(o2); lv.z = f2b(o2 - b2f(hv.z));
  hv.w = f2b(o3); lv.w = f2b(o3 - b2f(hv.w));
  *(ushort4*)(ohi + (size_t)row * DIM + t * 4) = hv;
  *(ushort4*)(olo + (size_t)row * DIM + t * 4) = lv;
}

// ---------------- weight prep: transpose KxN fp32 -> NxK bf16 hi/lo --------
__device__ __forceinline__ void wprep_body(const float* __restrict__ W,
                                           ushort* __restrict__ Whi,
                                           ushort* __restrict__ Wlo,
                                           int Kd, int Nd) {
  __shared__ float tile[64][65];
  const int t = threadIdx.x;
  const int n0 = blockIdx.x * 64, k0 = blockIdx.y * 64;
  const int r = t >> 4, c4 = (t & 15) * 4;
#pragma unroll
  for (int i = 0; i < 4; i++) {
    float4 v = *(const float4*)&W[(size_t)(k0 + r + i * 16) * Nd + n0 + c4];
    tile[r + i * 16][c4 + 0] = v.x;
    tile[r + i * 16][c4 + 1] = v.y;
    tile[r + i * 16][c4 + 2] = v.z;
    tile[r + i * 16][c4 + 3] = v.w;
  }
  __syncthreads();
#pragma unroll
  for (int i = 0; i < 4; i++) {
    int nr = r + i * 16;
    float x0 = tile[c4 + 0][nr], x1 = tile[c4 + 1][nr];
    float x2 = tile[c4 + 2][nr], x3 = tile[c4 + 3][nr];
    ushort4 hv, lv;
    hv.x = f2b(x0); lv.x = f2b(x0 - b2f(hv.x));
    hv.y = f2b(x1); lv.y = f2b(x1 - b2f(hv.y));
    hv.z = f2b(x2); lv.z = f2b(x2 - b2f(hv.z));
    hv.w = f2b(x3); lv.w = f2b(x3 - b2f(hv.w));
    *(ushort4*)&Whi[(size_t)(n0 + nr) * Kd + k0 + c4] = hv;
    *(ushort4*)&Wlo[(size_t)(n0 + nr) * Kd + k0 + c4] = lv;
  }
}

__global__ __launch_bounds__(256) void wprep_kernel(const float* __restrict__ W,
                                                    ushort* __restrict__ Whi,
                                                    ushort* __restrict__ Wlo,
                                                    int Kd, int Nd) {
  wprep_body(W, Whi, Wlo, Kd, Nd);
}

// 4 square DIM x DIM weights in one launch (z selects)
__global__ __launch_bounds__(256) void wprep4_kernel(
    const float* __restrict__ W0, const float* __restrict__ W1_,
    const float* __restrict__ W2_, const float* __restrict__ W3,
    ushort* __restrict__ H0, ushort* __restrict__ L0,
    ushort* __restrict__ H1, ushort* __restrict__ L1,
    ushort* __restrict__ H2, ushort* __restrict__ L2,
    ushort* __restrict__ H3, ushort* __restrict__ L3) {
  const float* W = (blockIdx.z == 0) ? W0 : (blockIdx.z == 1) ? W1_
                 : (blockIdx.z == 2) ? W2_ : W3;
  ushort* Wh = (blockIdx.z == 0) ? H0 : (blockIdx.z == 1) ? H1
             : (blockIdx.z == 2) ? H2 : H3;
  ushort* Wl = (blockIdx.z == 0) ? L0 : (blockIdx.z == 1) ? L1
             : (blockIdx.z == 2) ? L2 : L3;
  wprep_body(W, Wh, Wl, DIM, DIM);
}

// ---------------- split-bf16 MFMA GEMM (validated R4/R9/R11) ----------------
template <int MS, int NS, int EPI>
__device__ __forceinline__ void mgemm_body(
    const ushort* __restrict__ Ahi, const ushort* __restrict__ Alo,
    const ushort* __restrict__ Bhi, const ushort* __restrict__ Blo,
    const float* __restrict__ bias, const float* __restrict__ res,
    float* __restrict__ Cf, ushort* __restrict__ Chi, ushort* __restrict__ Clo,
    int M, int N, int Klen, int Kstride, int Koff) {
  constexpr int ASUB = 2 * MS;
  constexpr int BSUB = 2 * NS;
  constexpr int TOT = 2 * (ASUB + BSUB);
  constexpr int PW = TOT / 4;
  __shared__ ushort lds[TOT * 512];

  int bx, by;
  xcd_swz(bx, by);
  const int t = threadIdx.x;
  const int l = t & 63;
  const int wid = t >> 6;
  const int wm = wid >> 1, wn = wid & 1;
  const int m0 = by * (ASUB * 16);
  const int n0 = bx * (BSUB * 16);
  const int lr = l & 15;
  const int lk = (l >> 4) * 8;

  const ushort* gsrc[PW];
  ushort* ldst[PW];
#pragma unroll
  for (int i = 0; i < PW; i++) {
    int j = wid * PW + i;
    const ushort* base;
    int rowbase, slot;
    if (j < 2 * ASUB) {
      int plane = j & 1, sub = j >> 1;
      base = plane ? Alo : Ahi;
      rowbase = m0 + sub * 16;
      slot = plane * ASUB + sub;
    } else {
      int jb = j - 2 * ASUB;
      int plane = jb & 1, sub = jb >> 1;
      base = plane ? Blo : Bhi;
      rowbase = n0 + sub * 16;
      slot = 2 * ASUB + plane * BSUB + sub;
    }
    gsrc[i] = base + (size_t)(rowbase + lr) * Kstride + Koff + lk;
    ldst[i] = &lds[slot * 512];
  }

  f32x4 acc[MS][NS] = {};

  for (int k0 = 0; k0 < Klen; k0 += 32) {
    __syncthreads();
#pragma unroll
    for (int i = 0; i < PW; i++) {
      g2l16(gsrc[i], ldst[i]);
      gsrc[i] += 32;
    }
    __syncthreads();

    short8 ah[MS], al[MS], bh[NS], bl[NS];
#pragma unroll
    for (int mi = 0; mi < MS; mi++) {
      ah[mi] = *(const short8*)&lds[(wm * MS + mi) * 512 + l * 8];
      al[mi] = *(const short8*)&lds[(ASUB + wm * MS + mi) * 512 + l * 8];
    }
#pragma unroll
    for (int ni = 0; ni < NS; ni++) {
      bh[ni] = *(const short8*)&lds[(2 * ASUB + wn * NS + ni) * 512 + l * 8];
      bl[ni] = *(const short8*)&lds[(2 * ASUB + BSUB + wn * NS + ni) * 512 + l * 8];
    }
#pragma unroll
    for (int mi = 0; mi < MS; mi++)
#pragma unroll
      for (int ni = 0; ni < NS; ni++) {
        acc[mi][ni] = MFMA(ah[mi], bh[ni], acc[mi][ni]);
        acc[mi][ni] = MFMA(ah[mi], bl[ni], acc[mi][ni]);
        acc[mi][ni] = MFMA(al[mi], bh[ni], acc[mi][ni]);
      }
  }

  const int orow0 = m0 + wm * (MS * 16);
  const int ocol0 = n0 + wn * (NS * 16);
#pragma unroll
  for (int mi = 0; mi < MS; mi++) {
#pragma unroll
    for (int r = 0; r < 4; r++) {
      int row = orow0 + mi * 16 + (l >> 4) * 4 + r;
#pragma unroll
      for (int ni = 0; ni < NS; ni++) {
        int col = ocol0 + ni * 16 + lr;
        size_t idx = (size_t)row * N + col;
        float v = acc[mi][ni][r];
        if (EPI == 0) {
          Cf[idx] = v;
        } else if (EPI == 1) {
          Cf[idx] = v + res[idx];
        } else if (EPI == 2) {
          v += bias[col];
          v = 0.5f * v * (1.0f + erff(v * 0.70710678118654752f));
          ushort h = f2b(v);
          Chi[idx] = h;
          Clo[idx] = f2b(v - b2f(h));
        } else {
          Cf[idx] = v + bias[col] + res[idx];
        }
      }
    }
  }
}

template <int MS, int NS, int EPI, int MINW>
__global__ __launch_bounds__(256, MINW) void mgemm_kernel(
    const ushort* __restrict__ Ahi, const ushort* __restrict__ Alo,
    const ushort* __restrict__ Bhi, const ushort* __restrict__ Blo,
    const float* __restrict__ bias, const float* __restrict__ res,
    float* __restrict__ Cf, ushort* __restrict__ Chi, ushort* __restrict__ Clo,
    int M, int N, int K) {
  mgemm_body<MS, NS, EPI>(Ahi, Alo, Bhi, Blo, bias, res, Cf, Chi, Clo,
                          M, N, K, K, 0);
}

// split-K=4 at the 128x128 tile: z selects K-quarter (Wo only: 4 dead regions)
__global__ __launch_bounds__(256, 2) void mgemm_sk4(
    const ushort* __restrict__ Ahi, const ushort* __restrict__ Alo,
    const ushort* __restrict__ Bhi, const ushort* __restrict__ Blo,
    float* __restrict__ P0, float* __restrict__ P1,
    float* __restrict__ P2, float* __restrict__ P3,
    int M, int N, int K, int Kq) {
  float* P = (blockIdx.z == 0) ? P0 : (blockIdx.z == 1) ? P1
           : (blockIdx.z == 2) ? P2 : P3;
  mgemm_body<4, 4, 0>(Ahi, Alo, Bhi, Blo, nullptr, nullptr, P, nullptr,
                      nullptr, M, N, Kq, K, blockIdx.z * Kq);
}

// split-K=2 at the 128x128 tile (W2: only 3 dead 16MB regions exist; 2 used)
__global__ __launch_bounds__(256, 2) void mgemm_sk2(
    const ushort* __restrict__ Ahi, const ushort* __restrict__ Alo,
    const ushort* __restrict__ Bhi, const ushort* __restrict__ Blo,
    float* __restrict__ P0, float* __restrict__ P1,
    int M, int N, int K, int Kh) {
  float* P = blockIdx.z ? P1 : P0;
  mgemm_body<4, 4, 0>(Ahi, Alo, Bhi, Blo, nullptr, nullptr, P, nullptr,
                      nullptr, M, N, Kh, K, blockIdx.z * Kh);
}

// out = P0+P1+P2+P3 [+ bias] + res   (memory-bound, float4)
template <bool BIAS>
__global__ __launch_bounds__(256) void red4_kernel(const float* __restrict__ P0,
                                                   const float* __restrict__ P1,
                                                   const float* __restrict__ P2,
                                                   const float* __restrict__ P3,
                                                   const float* __restrict__ bias,
                                                   const float* __restrict__ res,
                                                   float* __restrict__ out) {
  size_t e = ((size_t)blockIdx.x * 256 + threadIdx.x) * 4;
  float4 a = *(const float4*)(P0 + e);
  float4 b = *(const float4*)(P1 + e);
  float4 c = *(const float4*)(P2 + e);
  float4 d = *(const float4*)(P3 + e);
  float4 r = *(const float4*)(res + e);
  float4 o;
  o.x = (a.x + b.x) + (c.x + d.x) + r.x;
  o.y = (a.y + b.y) + (c.y + d.y) + r.y;
  o.z = (a.z + b.z) + (c.z + d.z) + r.z;
  o.w = (a.w + b.w) + (c.w + d.w) + r.w;
  if (BIAS) {
    float4 bb = *(const float4*)(bias + (e & (DIM - 1)));
    o.x += bb.x; o.y += bb.y; o.z += bb.z; o.w += bb.w;
  }
  *(float4*)(out + e) = o;
}

// out = P0+P1 [+ bias] + res
template <bool BIAS>
__global__ __launch_bounds__(256) void red2_kernel(const float* __restrict__ P0,
                                                   const float* __restrict__ P1,
                                                   const float* __restrict__ bias,
                                                   const float* __restrict__ res,
                                                   float* __restrict__ out) {
  size_t e = ((size_t)blockIdx.x * 256 + threadIdx.x) * 4;
  float4 a = *(const float4*)(P0 + e);
  float4 b = *(const float4*)(P1 + e);
  float4 r = *(const float4*)(res + e);
  float4 o;
  o.x = a.x + b.x + r.x;
  o.y = a.y + b.y + r.y;
  o.z = a.z + b.z + r.z;
  o.w = a.w + b.w + r.w;
  if (BIAS) {
    float4 bb = *(const float4*)(bias + (e & (DIM - 1)));
    o.x += bb.x; o.y += bb.y; o.z += bb.z; o.w += bb.w;
  }
  *(float4*)(out + e) = o;
}

__global__ __launch_bounds__(256, 2) void qkv_mfma(
    const ushort* __restrict__ Ahi, const ushort* __restrict__ Alo,
    const ushort* __restrict__ Wqh, const ushort* __restrict__ Wql,
    const ushort* __restrict__ Wkh, const ushort* __restrict__ Wkl,
    const ushort* __restrict__ Wvh, const ushort* __restrict__ Wvl,
    float* __restrict__ Qo, float* __restrict__ Ko, float* __restrict__ Vo) {
  const ushort* bh = (blockIdx.z == 0) ? Wqh : (blockIdx.z == 1) ? Wkh : Wvh;
  const ushort* bl = (blockIdx.z == 0) ? Wql : (blockIdx.z == 1) ? Wkl : Wvl;
  float* C = (blockIdx.z == 0) ? Qo : (blockIdx.z == 1) ? Ko : Vo;
  mgemm_body<4, 4, 0>(Ahi, Alo, bh, bl, nullptr, nullptr, C, nullptr, nullptr,
                      4096, DIM, DIM, DIM, 0);
}

// ---------------- MFMA flash attention (validated R9) ----------------
#define KSLOT(s, ks, pl) (((s) * 2 + (ks)) * 1024 + (pl) * 512)
#define VSLOT(d, ks, pl) (8192 + ((d) * 2 + (ks)) * 1024 + (pl) * 512)
#define PSLOT(w, qf, ks, pl) (16384 + (w) * 4096 + (((qf) * 2 + (ks)) * 2 + (pl)) * 512)

__global__ __launch_bounds__(256, 2) void attn_mfma(const float* __restrict__ Q,
                                                    const float* __restrict__ K,
                                                    const float* __restrict__ V,
                                                    ushort* __restrict__ Ohi,
                                                    ushort* __restrict__ Olo) {
  __shared__ ushort lds[32768];   // 64 KB: K 16K + V^T 16K + P 4x8K
  const int qt = blockIdx.x;      // 0..7
  const int n  = blockIdx.y;      // 0..15
  const int bi = blockIdx.z;      // 0..3
  const size_t headoff = ((size_t)bi * SEQ + (size_t)n * HEADD) * DIM;
  const float* Qh = Q + headoff;
  const float* Kh = K + headoff;
  const float* Vh = V + headoff;
  const int t = threadIdx.x;
  const int l = t & 63;
  const int w = t >> 6;
  const int lq = l & 15;
  const int h = l >> 4;
  const int qrow = qt * 128 + w * 32;   // wave's first q row

  // Q fragments in registers: [qf][kstep] hi/lo
  short8 qfh[2][2], qfl[2][2];
#pragma unroll
  for (int qf = 0; qf < 2; qf++) {
    const float* qp = Qh + (size_t)(qrow + qf * 16 + lq) * 64 + h * 8;
#pragma unroll
    for (int ks = 0; ks < 2; ks++) {
      float f[8];
      float4 a = *(const float4*)(qp + ks * 32);
      float4 b = *(const float4*)(qp + ks * 32 + 4);
      f[0]=a.x; f[1]=a.y; f[2]=a.z; f[3]=a.w; f[4]=b.x; f[5]=b.y; f[6]=b.z; f[7]=b.w;
      cvt8(f, 1.0f, qfh[qf][ks], qfl[qf][ks]);
    }
  }

  f32x4 accO[4][2] = {};          // [df][qf], col=q lane-local
  float m_run[2] = {-1e30f, -1e30f};
  float l_run[2] = {0.0f, 0.0f};

  for (int tdx = 0; tdx < SEQ / 64; tdx++) {
    const int kvbase = tdx * 64;
    __syncthreads();
    // ---- stage K (wave w -> kv-subtile w), scale 1/8 folded (exact) ----
    {
      const float* kp = Kh + (size_t)(kvbase + 16 * w + lq) * 64 + h * 8;
#pragma unroll
      for (int ks = 0; ks < 2; ks++) {
        float f[8];
        float4 a = *(const float4*)(kp + ks * 32);
        float4 b = *(const float4*)(kp + ks * 32 + 4);
        f[0]=a.x; f[1]=a.y; f[2]=a.z; f[3]=a.w; f[4]=b.x; f[5]=b.y; f[6]=b.z; f[7]=b.w;
        short8 hi, lo;
        cvt8(f, 0.125f, hi, lo);
        *(short8*)&lds[KSLOT(w, ks, 0) + l * 8] = hi;
        *(short8*)&lds[KSLOT(w, ks, 1) + l * 8] = lo;
      }
    }
    // ---- stage V^T (wave w -> d-subtile w) ----
    {
#pragma unroll
      for (int ks = 0; ks < 2; ks++) {
        float f[8];
#pragma unroll
        for (int j = 0; j < 8; j++)
          f[j] = Vh[(size_t)(kvbase + ks * 32 + h * 8 + j) * 64 + 16 * w + lq];
        short8 hi, lo;
        cvt8(f, 1.0f, hi, lo);
        *(short8*)&lds[VSLOT(w, ks, 0) + l * 8] = hi;
        *(short8*)&lds[VSLOT(w, ks, 1) + l * 8] = lo;
      }
    }
    __syncthreads();

    // ---- S^T = K @ Q^T : acc row=kv, col=q (3-pass split) ----
    f32x4 accS[4][2] = {};
#pragma unroll
    for (int ks = 0; ks < 2; ks++) {
      short8 kh[4], kl[4];
#pragma unroll
      for (int s = 0; s < 4; s++) {
        kh[s] = *(const short8*)&lds[KSLOT(s, ks, 0) + l * 8];
        kl[s] = *(const short8*)&lds[KSLOT(s, ks, 1) + l * 8];
      }
#pragma unroll
      for (int s = 0; s < 4; s++)
#pragma unroll
        for (int qf = 0; qf < 2; qf++) {
          accS[s][qf] = MFMA(kh[s], qfh[qf][ks], accS[s][qf]);
          accS[s][qf] = MFMA(kh[s], qfl[qf][ks], accS[s][qf]);
          accS[s][qf] = MFMA(kl[s], qfh[qf][ks], accS[s][qf]);
        }
    }

    // ---- online softmax (per q = lane&15, per qf) ----
    float corr[2];
#pragma unroll
    for (int qf = 0; qf < 2; qf++) {
      float tmax = -1e30f;
#pragma unroll
      for (int s = 0; s < 4; s++)
#pragma unroll
        for (int r = 0; r < 4; r++) tmax = fmaxf(tmax, accS[s][qf][r]);
      tmax = fmaxf(tmax, __shfl_xor(tmax, 16));
      tmax = fmaxf(tmax, __shfl_xor(tmax, 32));
      float mnew = fmaxf(m_run[qf], tmax);
      float c = __expf(m_run[qf] - mnew);
      m_run[qf] = mnew;
      corr[qf] = c;
      float tsum = 0.0f;
#pragma unroll
      for (int s = 0; s < 4; s++)
#pragma unroll
        for (int r = 0; r < 4; r++) {
          float p = __expf(accS[s][qf][r] - mnew);
          accS[s][qf][r] = p;
          tsum += p;
        }
      tsum += __shfl_xor(tsum, 16);
      tsum += __shfl_xor(tsum, 32);
      l_run[qf] = l_run[qf] * c + tsum;
    }

    // ---- pack P -> wave-private LDS in B-fragment order ----
#pragma unroll
    for (int qf = 0; qf < 2; qf++)
#pragma unroll
      for (int s = 0; s < 4; s++) {
        f32x4 p = accS[s][qf];
        ushort4 hv, lv;
        hv.x = f2b(p[0]); lv.x = f2b(p[0] - b2f(hv.x));
        hv.y = f2b(p[1]); lv.y = f2b(p[1] - b2f(hv.y));
        hv.z = f2b(p[2]); lv.z = f2b(p[2] - b2f(hv.z));
        hv.w = f2b(p[3]); lv.w = f2b(p[3] - b2f(hv.w));
        int ib = (((s & 1) * 2) + (h >> 1)) * 128 + lq * 8 + (h & 1) * 4;
        *(ushort4*)&lds[PSLOT(w, qf, s >> 1, 0) + ib] = hv;
        *(ushort4*)&lds[PSLOT(w, qf, s >> 1, 1) + ib] = lv;
      }

    // ---- rescale O accumulator (corr lane-local: col=q) ----
#pragma unroll
    for (int df = 0; df < 4; df++)
#pragma unroll
      for (int qf = 0; qf < 2; qf++)
#pragma unroll
        for (int r = 0; r < 4; r++) accO[df][qf][r] *= corr[qf];

    // ---- O^T += V^T @ P^T (3-pass split) ----
#pragma unroll
    for (int ks = 0; ks < 2; ks++) {
      short8 vh[4], vl[4], ph[2], pl[2];
#pragma unroll
      for (int d = 0; d < 4; d++) {
        vh[d] = *(const short8*)&lds[VSLOT(d, ks, 0) + l * 8];
        vl[d] = *(const short8*)&lds[VSLOT(d, ks, 1) + l * 8];
      }
#pragma unroll
      for (int qf = 0; qf < 2; qf++) {
        ph[qf] = *(const short8*)&lds[PSLOT(w, qf, ks, 0) + l * 8];
        pl[qf] = *(const short8*)&lds[PSLOT(w, qf, ks, 1) + l * 8];
      }
#pragma unroll
      for (int d = 0; d < 4; d++)
#pragma unroll
        for (int qf = 0; qf < 2; qf++) {
          accO[d][qf] = MFMA(vh[d], ph[qf], accO[d][qf]);
          accO[d][qf] = MFMA(vl[d], ph[qf], accO[d][qf]);
          accO[d][qf] = MFMA(vh[d], pl[qf], accO[d][qf]);
        }
    }
  }

  // ---- epilogue: normalize + write bf16 hi/lo ----
#pragma unroll
  for (int qf = 0; qf < 2; qf++) {
    float inv = 1.0f / l_run[qf];
    int qg = qrow + qf * 16 + lq;
    size_t base = ((size_t)bi * SEQ + qg) * DIM + n * HEADD;
#pragma unroll
    for (int df = 0; df < 4; df++) {
      f32x4 o = accO[df][qf];
      float v0 = o[0] * inv, v1 = o[1] * inv, v2 = o[2] * inv, v3 = o[3] * inv;
      ushort4 hv, lv;
      hv.x = f2b(v0); lv.x = f2b(v0 - b2f(hv.x));
      hv.y = f2b(v1); lv.y = f2b(v1 - b2f(hv.y));
      hv.z = f2b(v2); lv.z = f2b(v2 - b2f(hv.z));
      hv.w = f2b(v3); lv.w = f2b(v3 - b2f(hv.w));
      size_t a = base + df * 16 + h * 4;
      *(ushort4*)(Ohi + a) = hv;
      *(ushort4*)(Olo + a) = lv;
    }
  }
}

// ---------------- launch ----------------
extern "C" void kernel_launch(void* const* d_in, const int* in_sizes, int n_in,
                              void* d_out, int out_size, void* d_ws, size_t ws_size,
                              hipStream_t stream) {
  const float* x    = (const float*)d_in[0];
  const float* Wq   = (const float*)d_in[1];
  const float* Wk   = (const float*)d_in[2];
  const float* Wv   = (const float*)d_in[3];
  const float* Wo   = (const float*)d_in[4];
  const float* W1   = (const float*)d_in[5];
  const float* b1   = (const float*)d_in[6];
  const float* W2   = (const float*)d_in[7];
  const float* b2   = (const float*)d_in[8];
  const float* gln1 = (const float*)d_in[9];
  const float* bln1 = (const float*)d_in[10];
  const float* gln2 = (const float*)d_in[11];
  const float* bln2 = (const float*)d_in[12];
  float* out = (float*)d_out;
  char* W = (char*)d_ws;

  const size_t MB = 1u << 20;
  ushort* Wqh = (ushort*)(W + 0 * MB);    // dead after qkv (step 2)
  ushort* Wql = (ushort*)(W + 2 * MB);
  ushort* Wkh = (ushort*)(W + 4 * MB);
  ushort* Wkl = (ushort*)(W + 6 * MB);
  ushort* Wvh = (ushort*)(W + 8 * MB);
  ushort* Wvl = (ushort*)(W + 10 * MB);
  ushort* Woh = (ushort*)(W + 12 * MB);   // dead after step 4a
  ushort* Wol = (ushort*)(W + 14 * MB);
  ushort* W1h = (ushort*)(W + 16 * MB);   // dead after step 6
  ushort* W1l = (ushort*)(W + 24 * MB);
  ushort* W2h = (ushort*)(W + 32 * MB);   // live till step 7a
  ushort* W2l = (ushort*)(W + 40 * MB);
  float*  X2  = (float*) (W + 48 * MB);   // live steps 4b-7b
  ushort* Hhi = (ushort*)(W + 64 * MB);   // LN1 out (1-2); LN2 out (5-6)
  ushort* Hlo = (ushort*)(W + 72 * MB);
  float*  Qb  = (float*) (W + 80 * MB);   // QKV fp32, dead after attn
  float*  Kb  = (float*) (W + 96 * MB);
  float*  Vb  = (float*) (W + 112 * MB);
  ushort* F1h = (ushort*)(W + 80 * MB);   // steps 6-7a (80-112MB)
  ushort* F1l = (ushort*)(W + 112 * MB);  // steps 6-7a (112-144MB)
  ushort* Ohi = (ushort*)(W + 128 * MB);  // attn out, dead after step 4a
  ushort* Olo = (ushort*)(W + 136 * MB);
  // Wo split-K=4 partials (fp32, 16 MB each) in regions dead at step 4a:
  float* Pwo[4] = {(float*)(W + 64 * MB),   // Hhi/Hlo dead (between qkv, LN2)
                   (float*)(W + 80 * MB),   // Qb dead after attn
                   (float*)(W + 96 * MB),   // Kb dead after attn
                   (float*)(W + 112 * MB)}; // Vb dead after attn
  // W2 split-K=2 partials: ONLY 0-16, 16-32, 64-80 MB are dead at step 7a
  // (W2h/W2l 32-48, X2 48-64, F1h 80-112, F1l 112-144 all live). R13's 4th
  // partial at 128MB raced F1l -> NaN. Two regions suffice for split-K=2.
  float* Pw2[2] = {(float*)(W + 0 * MB),    // qkv/Wo weights dead
                   (float*)(W + 16 * MB)};  // W1 weights dead after step 6

  // 0. weight prep (4 square weights fused into one launch)
  wprep4_kernel<<<dim3(16, 16, 4), 256, 0, stream>>>(
      Wq, Wk, Wv, Wo, Wqh, Wql, Wkh, Wkl, Wvh, Wvl, Woh, Wol);
  wprep_kernel<<<dim3(64, 16), 256, 0, stream>>>(W1, W1h, W1l, DIM, MLP_DIM);
  wprep_kernel<<<dim3(16, 64), 256, 0, stream>>>(W2, W2h, W2l, MLP_DIM, DIM);
  // 1. h = LN1(x)
  ln_kernel<<<4096, 256, 0, stream>>>(x, gln1, bln1, Hhi, Hlo);
  // 2. Q,K,V
  qkv_mfma<<<dim3(8, 32, 3), 256, 0, stream>>>(Hhi, Hlo, Wqh, Wql, Wkh, Wkl,
                                               Wvh, Wvl, Qb, Kb, Vb);
  // 3. attention
  attn_mfma<<<dim3(8, 16, 4), 256, 0, stream>>>(Qb, Kb, Vb, Ohi, Olo);
  // 4a. Wo split-K=4 (128x128 tile); 4b. X2 = sum(P) + x
  mgemm_sk4<<<dim3(8, 32, 4), 256, 0, stream>>>(
      Ohi, Olo, Woh, Wol, Pwo[0], Pwo[1], Pwo[2], Pwo[3],
      4096, DIM, DIM, DIM / 4);
  red4_kernel<false><<<4096, 256, 0, stream>>>(
      Pwo[0], Pwo[1], Pwo[2], Pwo[3], nullptr, x, X2);
  // 5. h2 = LN2(X2)
  ln_kernel<<<4096, 256, 0, stream>>>(X2, gln2, bln2, Hhi, Hlo);
  // 6. f1 = gelu(h2 @ W1 + b1)
  mgemm_kernel<4, 4, 2, 2><<<dim3(32, 32), 256, 0, stream>>>(
      Hhi, Hlo, W1h, W1l, b1, nullptr, nullptr, F1h, F1l, 4096, MLP_DIM, DIM);
  // 7a. W2 split-K=2 (128x128 tile); 7b. out = P0+P1+b2+X2
  mgemm_sk2<<<dim3(8, 32, 2), 256, 0, stream>>>(
      F1h, F1l, W2h, W2l, Pw2[0], Pw2[1],
      4096, DIM, MLP_DIM, MLP_DIM / 2);
  red2_kernel<true><<<4096, 256, 0, stream>>>(Pw2[0], Pw2[1], b2, X2, out);
}